// Round 8
// baseline (595.102 us; speedup 1.0000x reference)
//
#include <hip/hip_runtime.h>
#include <hip/hip_bf16.h>
#include <math.h>

#define SS 2048
#define HH 1024
#define NHEADS 16
#define NKVH 4
#define HDIM 64
#define NEXP 8
#define FDIM 2048

static constexpr float EPSV   = 1e-6f;
static constexpr float ALPHAV = 1.702f;
static constexpr float LIMITV = 7.0f;

typedef __attribute__((ext_vector_type(8))) short bf16x8;
typedef __attribute__((ext_vector_type(4))) float f32x4;

__device__ __forceinline__ float wave_reduce_sum(float v) {
#pragma unroll
  for (int off = 32; off; off >>= 1) v += __shfl_xor(v, off);
  return v;
}

__device__ __forceinline__ void gload_lds16(const __hip_bfloat16* g, __hip_bfloat16* s) {
  __builtin_amdgcn_global_load_lds(
      (const __attribute__((address_space(1))) void*)g,
      (__attribute__((address_space(3))) void*)s, 16, 0, 0);
}

// ---------------- RMSNorm: fp32 in, optional fp32 out + bf16 out -----------
__global__ void rmsnorm_kernel(const float* __restrict__ x,
                               const float* __restrict__ w,
                               float* __restrict__ o32,
                               __hip_bfloat16* __restrict__ o16) {
  int row = blockIdx.x;
  int t = threadIdx.x;
  const float4 v = ((const float4*)(x + (size_t)row * HH))[t];
  float ss = v.x * v.x + v.y * v.y + v.z * v.z + v.w * v.w;
  ss = wave_reduce_sum(ss);
  __shared__ float parts[4];
  if ((t & 63) == 0) parts[t >> 6] = ss;
  __syncthreads();
  float tot = parts[0] + parts[1] + parts[2] + parts[3];
  float r = rsqrtf(tot * (1.0f / HH) + EPSV);
  const float4 ww = ((const float4*)w)[t];
  float4 out;
  out.x = v.x * r * ww.x;
  out.y = v.y * r * ww.y;
  out.z = v.z * r * ww.z;
  out.w = v.w * r * ww.w;
  if (o32) ((float4*)(o32 + (size_t)row * HH))[t] = out;
  __hip_bfloat16* d = o16 + (size_t)row * HH + t * 4;
  d[0] = __float2bfloat16(out.x);
  d[1] = __float2bfloat16(out.y);
  d[2] = __float2bfloat16(out.z);
  d[3] = __float2bfloat16(out.w);
}

// ---------------- Transpose-cast: in[R][C] fp32 -> out[C][R] bf16 ----------
__global__ void tcast_kernel(const float* __restrict__ in,
                             __hip_bfloat16* __restrict__ out,
                             int R, int C, size_t inBatch, size_t outBatch) {
  const float* ip = in + blockIdx.z * inBatch;
  __hip_bfloat16* op = out + blockIdx.z * outBatch;
  __shared__ float tile[32][33];
  int c0 = blockIdx.x * 32, r0 = blockIdx.y * 32;
  int tx = threadIdx.x & 31, ty = threadIdx.x >> 5;  // ty 0..7
#pragma unroll
  for (int j = 0; j < 4; ++j)
    tile[ty * 4 + j][tx] = ip[(size_t)(r0 + ty * 4 + j) * C + c0 + tx];
  __syncthreads();
#pragma unroll
  for (int j = 0; j < 4; ++j)
    op[(size_t)(c0 + ty * 4 + j) * R + r0 + tx] = __float2bfloat16(tile[tx][ty * 4 + j]);
}

// ---------------- MFMA bf16 GEMM: C[M,N] = A[M,K] @ Bt[N,K]^T --------------
template <int MODE>
__global__ __launch_bounds__(256) void mfma_gemm(
    const __hip_bfloat16* __restrict__ A,
    const __hip_bfloat16* __restrict__ Bt,
    float* __restrict__ Cf, __hip_bfloat16* __restrict__ Cb,
    const float* __restrict__ addend, const float* __restrict__ bias,
    const int* __restrict__ counts, const int* __restrict__ offsets,
    const int* __restrict__ tos, int M0, int N, int K) {
  int e = blockIdx.z;
  int M = M0, off = 0;
  if (MODE >= 2) { M = counts[e]; off = offsets[e]; }
  int row0 = blockIdx.y * 128;
  if (row0 >= M) return;
  int n0 = blockIdx.x * 128;
  const __hip_bfloat16* Bte = Bt + (size_t)e * ((size_t)N * K);
  __shared__ __align__(16) __hip_bfloat16 sA[128 * 32];
  __shared__ __align__(16) __hip_bfloat16 sB[128 * 32];
  int t = threadIdx.x;
  int lane = t & 63;
  int wm = t >> 7, wn = (t >> 6) & 1;
  f32x4 acc[4][4] = {};

  int arow[2];
#pragma unroll
  for (int i = 0; i < 2; ++i) {
    int rg = row0 + i * 64 + (t >> 2);
    int ar;
    if (MODE == 2)      ar = (rg < M) ? tos[off + rg] : tos[off];
    else if (MODE == 3) ar = off + ((rg < M) ? rg : 0);
    else                ar = rg;
    arow[i] = ar;
  }
  int brow0 = n0 + (t >> 2);
  int kc = (t & 3) * 8;

  for (int k0 = 0; k0 < K; k0 += 32) {
#pragma unroll
    for (int i = 0; i < 2; ++i) {
      int r = i * 64 + (t >> 2);
      gload_lds16(A + (size_t)arow[i] * K + k0 + kc, sA + r * 32 + kc);
      gload_lds16(Bte + (size_t)(brow0 + i * 64) * K + k0 + kc, sB + r * 32 + kc);
    }
    __syncthreads();
    bf16x8 af[4], bfr[4];
#pragma unroll
    for (int mi = 0; mi < 4; ++mi)
      af[mi] = *(const bf16x8*)(sA + (wm * 64 + mi * 16 + (lane & 15)) * 32 + (lane >> 4) * 8);
#pragma unroll
    for (int ni = 0; ni < 4; ++ni)
      bfr[ni] = *(const bf16x8*)(sB + (wn * 64 + ni * 16 + (lane & 15)) * 32 + (lane >> 4) * 8);
#pragma unroll
    for (int mi = 0; mi < 4; ++mi)
#pragma unroll
      for (int ni = 0; ni < 4; ++ni)
        acc[mi][ni] = __builtin_amdgcn_mfma_f32_16x16x32_bf16(af[mi], bfr[ni], acc[mi][ni], 0, 0, 0);
    __syncthreads();
  }

#pragma unroll
  for (int mi = 0; mi < 4; ++mi) {
#pragma unroll
    for (int ni = 0; ni < 4; ++ni) {
      int col = n0 + wn * 64 + ni * 16 + (lane & 15);
#pragma unroll
      for (int j = 0; j < 4; ++j) {
        float v = acc[mi][ni][j];
        int rg = row0 + wm * 64 + mi * 16 + (lane >> 4) * 4 + j;
        if (MODE == 0) {
          Cf[(size_t)rg * N + col] = v;
        } else if (MODE == 1) {
          Cf[(size_t)rg * N + col] = v + addend[(size_t)rg * N + col];
        } else if (MODE == 2) {
          float other = __shfl_xor(v, 1);
          if (!(lane & 1) && rg < M) {
            float gate = fminf(v + bias[(size_t)e * N + col], LIMITV);
            float up = fminf(fmaxf(other + bias[(size_t)e * N + col + 1], -LIMITV), LIMITV);
            float glu = gate / (1.f + __expf(-gate * ALPHAV));
            Cb[(size_t)(off + rg) * (N / 2) + (col >> 1)] = __float2bfloat16((up + 1.f) * glu);
          }
        } else {
          if (rg < M)
            Cf[(size_t)(off + rg) * N + col] = v + bias[(size_t)e * N + col];
        }
      }
    }
  }
}

// ---------------- RoPE + hi/lo split cast ----------------------------------
__global__ __launch_bounds__(512) void rope_cast_kernel(
    const float* __restrict__ qkv, const float* __restrict__ sins,
    const float* __restrict__ coss,
    __hip_bfloat16* __restrict__ qhi, __hip_bfloat16* __restrict__ qlo,
    __hip_bfloat16* __restrict__ khi, __hip_bfloat16* __restrict__ klo) {
  int s = blockIdx.x, t = threadIdx.x;
  const float* rowp = qkv + (size_t)s * 1536;
  int hh = t >> 5, j = t & 31;
  float c = coss[s * 32 + j], sn = sins[s * 32 + j];
  {
    float xr = rowp[hh * 64 + j], xi = rowp[hh * 64 + 32 + j];
    float y0 = xr * c - xi * sn;
    float y1 = xr * sn + xi * c;
    size_t i0 = (size_t)s * 1024 + hh * 64 + j;
    __hip_bfloat16 h0 = __float2bfloat16(y0);
    __hip_bfloat16 h1 = __float2bfloat16(y1);
    qhi[i0] = h0;      qlo[i0] = __float2bfloat16(y0 - __bfloat162float(h0));
    qhi[i0 + 32] = h1; qlo[i0 + 32] = __float2bfloat16(y1 - __bfloat162float(h1));
  }
  if (t < 128) {
    int kh = t >> 5;
    float xr = rowp[1024 + kh * 64 + j], xi = rowp[1024 + kh * 64 + 32 + j];
    float y0 = xr * c - xi * sn;
    float y1 = xr * sn + xi * c;
    size_t i0 = (size_t)kh * 131072 + s * 64 + j;
    __hip_bfloat16 h0 = __float2bfloat16(y0);
    __hip_bfloat16 h1 = __float2bfloat16(y1);
    khi[i0] = h0;      klo[i0] = __float2bfloat16(y0 - __bfloat162float(h0));
    khi[i0 + 32] = h1; klo[i0 + 32] = __float2bfloat16(y1 - __bfloat162float(h1));
  }
}

// ---------------- V transpose: qkv fp32 v-part -> vT bf16 [4][64][2048] ----
__global__ void vtrans_kernel(const float* __restrict__ qkv,
                              __hip_bfloat16* __restrict__ vT) {
  __shared__ float tile[32][33];
  int kh = blockIdx.z;
  int d0 = blockIdx.x * 32;
  int s0 = blockIdx.y * 32;
  int tx = threadIdx.x & 31, ty = threadIdx.x >> 5;  // ty 0..7
#pragma unroll
  for (int j = 0; j < 4; ++j)
    tile[ty * 4 + j][tx] =
        qkv[(size_t)(s0 + ty * 4 + j) * 1536 + 1280 + kh * 64 + d0 + tx];
  __syncthreads();
#pragma unroll
  for (int j = 0; j < 4; ++j)
    vT[(size_t)kh * 131072 + (size_t)(d0 + ty * 4 + j) * 2048 + s0 + tx] =
        __float2bfloat16(tile[tx][ty * 4 + j]);
}

// ---------------- MFMA flash attention, kv-split, hi/lo precision ----------
// grid (32 qgroups, 16 heads, 4 kv-chunks), 256 thr = 4 waves, each wave
// owns q-tile qb = 4*qg + wq (16 rows). Zero barriers: waves independent.
// Chunk ck covers kv-tiles [8ck, min(8ck+8, qg+1)). Partials to scratch.
__global__ __launch_bounds__(256) void mfma_attn(
    const __hip_bfloat16* __restrict__ qhi, const __hip_bfloat16* __restrict__ qlo,
    const __hip_bfloat16* __restrict__ khi, const __hip_bfloat16* __restrict__ klo,
    const __hip_bfloat16* __restrict__ vT,  // [4][64][S]
    float* __restrict__ pacc,               // [4][S][1024] unnormalized O
    float* __restrict__ pm,                 // [4][16][S]
    float* __restrict__ pl) {               // [4][16][S]
  __shared__ __align__(16) __hip_bfloat16 sPh[4][16 * 80];
  __shared__ __align__(16) __hip_bfloat16 sPl[4][16 * 80];
  int qg = blockIdx.x;
  int h = blockIdx.y, kh = h >> 2;
  int ck = blockIdx.z;
  if (8 * ck > qg) return;   // block-uniform (qb/4 == qg for all 4 waves)
  int t = threadIdx.x, lane = t & 63, wq = t >> 6;
  int qb = qg * 4 + wq;
  int qrow0 = qb * 16;
  const int koff = (lane >> 4) * 8;  // elems

  bf16x8 aqh[2], aql[2];
  {
    size_t qo = (size_t)(qrow0 + (lane & 15)) * 1024 + h * 64;
    aqh[0] = *(const bf16x8*)(qhi + qo + koff);
    aqh[1] = *(const bf16x8*)(qhi + qo + 32 + koff);
    aql[0] = *(const bf16x8*)(qlo + qo + koff);
    aql[1] = *(const bf16x8*)(qlo + qo + 32 + koff);
  }
  f32x4 acc_o[4] = {};
  float m[4] = {-1e30f, -1e30f, -1e30f, -1e30f};
  float l[4] = {};
  const size_t kbase = (size_t)kh * (SS * 64) + (size_t)(lane & 15) * 64 + koff;
  const __hip_bfloat16* khp = khi + kbase;
  const __hip_bfloat16* klp = klo + kbase;
  const __hip_bfloat16* vfp =
      vT + (size_t)kh * (64 * SS) + (size_t)(lane & 15) * SS + koff;
  __hip_bfloat16* sPhw = sPh[wq];
  __hip_bfloat16* sPlw = sPl[wq];

  int ntiles = qb / 4 + 1;   // == qg + 1
  int lastT = ntiles - 1;
  int t0 = 8 * ck;
  int t1 = 8 * ck + 8; if (t1 > ntiles) t1 = ntiles;

  for (int tile = t0; tile < t1; ++tile) {
    int kv0 = tile * 64;
    bool last = (tile == lastT);

    // S = Q K^T with hi/lo split
    f32x4 sacc[4] = {};
#pragma unroll
    for (int n = 0; n < 4; ++n) {
#pragma unroll
      for (int step = 0; step < 2; ++step) {
        size_t ko = (size_t)(kv0 + n * 16) * 64 + step * 32;
        bf16x8 bkh = *(const bf16x8*)(khp + ko);
        bf16x8 bkl = *(const bf16x8*)(klp + ko);
        sacc[n] = __builtin_amdgcn_mfma_f32_16x16x32_bf16(aqh[step], bkh, sacc[n], 0, 0, 0);
        sacc[n] = __builtin_amdgcn_mfma_f32_16x16x32_bf16(aqh[step], bkl, sacc[n], 0, 0, 0);
        sacc[n] = __builtin_amdgcn_mfma_f32_16x16x32_bf16(aql[step], bkh, sacc[n], 0, 0, 0);
      }
    }

    // online softmax per j-row (C layout: row=(lane>>4)*4+j, col=n*16+(lane&15))
    float alpha[4];
#pragma unroll
    for (int j = 0; j < 4; ++j) {
      int qr = qrow0 + (lane >> 4) * 4 + j;
      float sv[4];
#pragma unroll
      for (int n = 0; n < 4; ++n) {
        float s = sacc[n][j] * 0.125f;
        if (last && (kv0 + n * 16 + (lane & 15)) > qr) s = -1e30f;
        sv[n] = s;
      }
      float smax = fmaxf(fmaxf(sv[0], sv[1]), fmaxf(sv[2], sv[3]));
#pragma unroll
      for (int msk = 1; msk < 16; msk <<= 1) smax = fmaxf(smax, __shfl_xor(smax, msk));
      float mnew = fmaxf(m[j], smax);
      float a = __expf(m[j] - mnew);
      float rs = 0.f;
      int prow = (lane >> 4) * 4 + j;
#pragma unroll
      for (int n = 0; n < 4; ++n) {
        float p = __expf(sv[n] - mnew);
        rs += p;
        __hip_bfloat16 ph = __float2bfloat16(p);
        sPhw[prow * 80 + n * 16 + (lane & 15)] = ph;
        sPlw[prow * 80 + n * 16 + (lane & 15)] =
            __float2bfloat16(p - __bfloat162float(ph));
      }
#pragma unroll
      for (int msk = 1; msk < 16; msk <<= 1) rs += __shfl_xor(rs, msk);
      l[j] = l[j] * a + rs;
      m[j] = mnew;
      alpha[j] = a;
    }
#pragma unroll
    for (int n2 = 0; n2 < 4; ++n2)
#pragma unroll
      for (int j = 0; j < 4; ++j) acc_o[n2][j] *= alpha[j];

    // O += P V with hi/lo P (same-wave LDS, no barrier needed)
#pragma unroll
    for (int n2 = 0; n2 < 4; ++n2) {
#pragma unroll
      for (int step = 0; step < 2; ++step) {
        bf16x8 aph = *(const bf16x8*)(sPhw + (lane & 15) * 80 + koff + step * 32);
        bf16x8 apl = *(const bf16x8*)(sPlw + (lane & 15) * 80 + koff + step * 32);
        bf16x8 bv = *(const bf16x8*)(vfp + (size_t)(n2 * 16) * SS + kv0 + step * 32);
        acc_o[n2] = __builtin_amdgcn_mfma_f32_16x16x32_bf16(aph, bv, acc_o[n2], 0, 0, 0);
        acc_o[n2] = __builtin_amdgcn_mfma_f32_16x16x32_bf16(apl, bv, acc_o[n2], 0, 0, 0);
      }
    }
  }

  // store partials (unnormalized)
#pragma unroll
  for (int n2 = 0; n2 < 4; ++n2) {
#pragma unroll
    for (int j = 0; j < 4; ++j) {
      int row = qrow0 + (lane >> 4) * 4 + j;
      pacc[((size_t)ck * SS + row) * 1024 + h * 64 + n2 * 16 + (lane & 15)] = acc_o[n2][j];
    }
  }
  if ((lane & 15) == 0) {
#pragma unroll
    for (int j = 0; j < 4; ++j) {
      int row = qrow0 + (lane >> 4) * 4 + j;
      pm[(ck * 16 + h) * SS + row] = m[j];
      pl[(ck * 16 + h) * SS + row] = l[j];
    }
  }
}

// ---------------- Attention merge: combine <=4 kv-chunk partials -----------
__global__ __launch_bounds__(256) void attn_merge(
    const float* __restrict__ pacc, const float* __restrict__ pm,
    const float* __restrict__ pl, __hip_bfloat16* __restrict__ o) {
  int r = blockIdx.x;
  int t = threadIdx.x;
  int col = t * 4;
  int h = col >> 6;
  int nch = r / 512 + 1;
  float M = -1e30f;
  for (int c = 0; c < nch; ++c) M = fmaxf(M, pm[(c * 16 + h) * SS + r]);
  float L = 0.f;
  float4 acc = {0.f, 0.f, 0.f, 0.f};
  for (int c = 0; c < nch; ++c) {
    float w = __expf(pm[(c * 16 + h) * SS + r] - M);
    L += w * pl[(c * 16 + h) * SS + r];
    float4 a = *(const float4*)(pacc + ((size_t)c * SS + r) * 1024 + col);
    acc.x += w * a.x; acc.y += w * a.y; acc.z += w * a.z; acc.w += w * a.w;
  }
  float inv = 1.f / L;
  __hip_bfloat16* d = o + (size_t)r * 1024 + col;
  d[0] = __float2bfloat16(acc.x * inv);
  d[1] = __float2bfloat16(acc.y * inv);
  d[2] = __float2bfloat16(acc.z * inv);
  d[3] = __float2bfloat16(acc.w * inv);
}

// ---------------- Router ---------------------------------------------------
__global__ void router_kernel(const float* __restrict__ xn2,
                              const float* __restrict__ wr,
                              const float* __restrict__ br,
                              int* __restrict__ tok_e, float* __restrict__ tok_w,
                              int* __restrict__ counts) {
  int tok = blockIdx.x, lane = threadIdx.x;
  const float* x = xn2 + (size_t)tok * HH;
  float lg[NEXP];
#pragma unroll
  for (int e = 0; e < NEXP; ++e) {
    float p = 0.f;
    for (int d = lane; d < HH; d += 64) p += x[d] * wr[d * NEXP + e];
    p = wave_reduce_sum(p);
    lg[e] = p + br[e];
  }
  if (lane == 0) {
    int e0 = 0; float v0 = lg[0];
#pragma unroll
    for (int e = 1; e < NEXP; ++e) if (lg[e] > v0) { v0 = lg[e]; e0 = e; }
    int e1 = -1; float v1 = -1e30f;
#pragma unroll
    for (int e = 0; e < NEXP; ++e)
      if (e != e0 && lg[e] > v1) { v1 = lg[e]; e1 = e; }
    float z = __expf(v1 - v0);
    float w0 = 1.f / (1.f + z);
    tok_e[2 * tok] = e0; tok_e[2 * tok + 1] = e1;
    tok_w[2 * tok] = w0; tok_w[2 * tok + 1] = 1.f - w0;
    atomicAdd(&counts[e0], 1);
    atomicAdd(&counts[e1], 1);
  }
}

__global__ void offsets_kernel(const int* __restrict__ counts,
                               int* __restrict__ offsets, int* __restrict__ cursor) {
  int s = 0;
#pragma unroll
  for (int e = 0; e < NEXP; ++e) { offsets[e] = s; s += counts[e]; cursor[e] = 0; }
}

__global__ void scatter_kernel(const int* __restrict__ tok_e,
                               const int* __restrict__ offsets, int* __restrict__ cursor,
                               int* __restrict__ token_of_slot,
                               int* __restrict__ slot_of_token) {
  int tok = blockIdx.x * 64 + threadIdx.x;
#pragma unroll
  for (int s2 = 0; s2 < 2; ++s2) {
    int e = tok_e[2 * tok + s2];
    int pos = atomicAdd(&cursor[e], 1);
    int g = offsets[e] + pos;
    token_of_slot[g] = tok;
    slot_of_token[2 * tok + s2] = g;
  }
}

// ---------------- Final combine -------------------------------------------
__global__ void combine_kernel(const float* __restrict__ resid2,
                               const float* __restrict__ dout,
                               const int* __restrict__ slot_of_token,
                               const float* __restrict__ tok_w,
                               float* __restrict__ out) {
  int tok = blockIdx.x;
  int g0 = slot_of_token[2 * tok], g1 = slot_of_token[2 * tok + 1];
  float w0 = tok_w[2 * tok], w1 = tok_w[2 * tok + 1];
  int i = threadIdx.x;
  float4 r = ((const float4*)(resid2 + (size_t)tok * HH))[i];
  float4 a = ((const float4*)(dout + (size_t)g0 * HH))[i];
  float4 b = ((const float4*)(dout + (size_t)g1 * HH))[i];
  float4 o;
  o.x = r.x + w0 * a.x + w1 * b.x;
  o.y = r.y + w0 * a.y + w1 * b.y;
  o.z = r.z + w0 * a.z + w1 * b.z;
  o.w = r.w + w0 * a.w + w1 * b.w;
  ((float4*)(out + (size_t)tok * HH))[i] = o;
}

extern "C" void kernel_launch(void* const* d_in, const int* in_sizes, int n_in,
                              void* d_out, int out_size, void* d_ws, size_t ws_size,
                              hipStream_t stream) {
  const float* hidden = (const float*)d_in[0];
  const float* sins   = (const float*)d_in[1];
  const float* coss   = (const float*)d_in[2];
  const float* ln1_w  = (const float*)d_in[4];
  const float* ln2_w  = (const float*)d_in[5];
  const float* wq     = (const float*)d_in[6];
  const float* wk     = (const float*)d_in[7];
  const float* wv     = (const float*)d_in[8];
  const float* wo     = (const float*)d_in[9];
  const float* w_router = (const float*)d_in[10];
  const float* b_router = (const float*)d_in[11];
  const float* gup    = (const float*)d_in[12];
  const float* gub    = (const float*)d_in[13];
  const float* dp     = (const float*)d_in[14];
  const float* db     = (const float*)d_in[15];
  float* out = (float*)d_out;

  float* ws = (float*)d_ws;
  float* resid2 = ws;                                      // 2,097,152 f
  float* xn2    = resid2 + 2097152;                        // 2,097,152 f
  __hip_bfloat16* xn2b = (__hip_bfloat16*)(xn2 + 2097152); // 2M bf16
  float* pa = xn2 + 2097152 + 1048576;
  // phase A carve (dead after WO GEMM; reused as dpT in phase B)
  __hip_bfloat16* xn1b = (__hip_bfloat16*)pa;              // [0, 1,048,576) f
  __hip_bfloat16* qlo_b = (__hip_bfloat16*)pa;             // over xn1b (dead by rope)
  float* qkv = pa + 1048576;                               // [1,048,576, 4,194,304)
  __hip_bfloat16* qkvT = (__hip_bfloat16*)(pa + 4194304);  // [4,194,304, 4,980,736)
  __hip_bfloat16* woT  = qkvT + 1572864;                   // [4,980,736, 5,505,024)
  __hip_bfloat16* qhi_b = (__hip_bfloat16*)(pa + 5505024); // [5,505,024, 6,553,600)
  __hip_bfloat16* khi_b = qhi_b + 2097152;                 // [6,553,600, 6,815,744)
  __hip_bfloat16* vTb  = khi_b + 524288;                   // [6,815,744, 7,077,888)
  __hip_bfloat16* attnb = (__hip_bfloat16*)(pa + 7077888); // [7,077,888, 8,126,464)
  __hip_bfloat16* klo_b = (__hip_bfloat16*)(pa + 8126464); // [8,126,464, 8,388,608)
  __hip_bfloat16* dpT = (__hip_bfloat16*)pa;               // phase B: [0, 8,388,608)
  float* pb = pa + 8388608;
  __hip_bfloat16* gupT = (__hip_bfloat16*)pb;              // 33.55M bf16 (phase B)
  // attn partials alias the gupT region (phase A only, dead before tcast gup)
  float* pacc = pb;                                        // 4*2048*1024 = 8,388,608 f
  float* pm_b = pb + 8388608;                              // 131,072 f
  float* pl_b = pm_b + 131072;                             // 131,072 f
  __hip_bfloat16* gatedb = gupT + 33554432;                // 8.39M bf16
  float* dout = pb + 16777216 + 4194304;                   // 4,194,304 f
  float* tok_w = dout + 4194304;
  int* counts = (int*)(tok_w + 4096);
  int* offsets = counts + 8;
  int* cursor = offsets + 8;
  int* tok_e = cursor + 8;
  int* token_of_slot = tok_e + 4096;
  int* slot_of_token = token_of_slot + 4096;

  rmsnorm_kernel<<<SS, 256, 0, stream>>>(hidden, ln1_w, nullptr, xn1b);
  tcast_kernel<<<dim3(32, 32, 1), 256, 0, stream>>>(wq, qkvT, 1024, 1024, 0, 0);
  tcast_kernel<<<dim3(8, 32, 1), 256, 0, stream>>>(wk, qkvT + 1024 * 1024, 1024, 256, 0, 0);
  tcast_kernel<<<dim3(8, 32, 1), 256, 0, stream>>>(wv, qkvT + 1280 * 1024, 1024, 256, 0, 0);
  tcast_kernel<<<dim3(32, 32, 1), 256, 0, stream>>>(wo, woT, 1024, 1024, 0, 0);
  mfma_gemm<0><<<dim3(12, 16, 1), 256, 0, stream>>>(
      xn1b, qkvT, qkv, nullptr, nullptr, nullptr, nullptr, nullptr, nullptr, SS, 1536, 1024);
  rope_cast_kernel<<<SS, 512, 0, stream>>>(qkv, sins, coss, qhi_b, qlo_b, khi_b, klo_b);
  vtrans_kernel<<<dim3(2, 64, 4), 256, 0, stream>>>(qkv, vTb);
  mfma_attn<<<dim3(32, 16, 4), 256, 0, stream>>>(
      qhi_b, qlo_b, khi_b, klo_b, vTb, pacc, pm_b, pl_b);
  attn_merge<<<SS, 256, 0, stream>>>(pacc, pm_b, pl_b, attnb);
  mfma_gemm<1><<<dim3(8, 16, 1), 256, 0, stream>>>(
      attnb, woT, resid2, nullptr, hidden, nullptr, nullptr, nullptr, nullptr, SS, 1024, 1024);
  rmsnorm_kernel<<<SS, 256, 0, stream>>>(resid2, ln2_w, xn2, xn2b);
  tcast_kernel<<<dim3(32, 64, NEXP), 256, 0, stream>>>(
      dp, dpT, 2048, 1024, (size_t)2048 * 1024, (size_t)1024 * 2048);
  tcast_kernel<<<dim3(128, 32, NEXP), 256, 0, stream>>>(
      gup, gupT, 1024, 4096, (size_t)1024 * 4096, (size_t)4096 * 1024);
  hipMemsetAsync(counts, 0, 8 * sizeof(int), stream);
  router_kernel<<<SS, 64, 0, stream>>>(xn2, w_router, b_router, tok_e, tok_w, counts);
  offsets_kernel<<<1, 1, 0, stream>>>(counts, offsets, cursor);
  scatter_kernel<<<SS / 64, 64, 0, stream>>>(tok_e, offsets, cursor, token_of_slot, slot_of_token);
  mfma_gemm<2><<<dim3(32, 16, NEXP), 256, 0, stream>>>(
      xn2b, gupT, nullptr, gatedb, nullptr, gub, counts, offsets, token_of_slot, 0, 4096, 1024);
  mfma_gemm<3><<<dim3(8, 16, NEXP), 256, 0, stream>>>(
      gatedb, dpT, dout, nullptr, nullptr, db, counts, offsets, nullptr, 0, 1024, 2048);
  combine_kernel<<<SS, 256, 0, stream>>>(resid2, dout, slot_of_token, tok_w, out);
}

// Round 10
// 546.478 us; speedup vs baseline: 1.0890x; 1.0890x over previous
//
#include <hip/hip_runtime.h>
#include <hip/hip_bf16.h>
#include <math.h>

#define SS 2048
#define HH 1024
#define NHEADS 16
#define NKVH 4
#define HDIM 64
#define NEXP 8
#define FDIM 2048

static constexpr float EPSV   = 1e-6f;
static constexpr float ALPHAV = 1.702f;
static constexpr float LIMITV = 7.0f;

typedef __attribute__((ext_vector_type(8))) short bf16x8;
typedef __attribute__((ext_vector_type(4))) float f32x4;

__device__ __forceinline__ float wave_reduce_sum(float v) {
#pragma unroll
  for (int off = 32; off; off >>= 1) v += __shfl_xor(v, off);
  return v;
}

__device__ __forceinline__ unsigned short bf16_bits(float x) {
  __hip_bfloat16 h = __float2bfloat16(x);
  return *reinterpret_cast<unsigned short*>(&h);
}

__device__ __forceinline__ void gload_lds16(const __hip_bfloat16* g, __hip_bfloat16* s) {
  __builtin_amdgcn_global_load_lds(
      (const __attribute__((address_space(1))) void*)g,
      (__attribute__((address_space(3))) void*)s, 16, 0, 0);
}

// ---------------- RMSNorm: fp32 in, optional fp32 out + bf16 out -----------
__global__ void rmsnorm_kernel(const float* __restrict__ x,
                               const float* __restrict__ w,
                               float* __restrict__ o32,
                               __hip_bfloat16* __restrict__ o16) {
  int row = blockIdx.x;
  int t = threadIdx.x;
  const float4 v = ((const float4*)(x + (size_t)row * HH))[t];
  float ss = v.x * v.x + v.y * v.y + v.z * v.z + v.w * v.w;
  ss = wave_reduce_sum(ss);
  __shared__ float parts[4];
  if ((t & 63) == 0) parts[t >> 6] = ss;
  __syncthreads();
  float tot = parts[0] + parts[1] + parts[2] + parts[3];
  float r = rsqrtf(tot * (1.0f / HH) + EPSV);
  const float4 ww = ((const float4*)w)[t];
  float4 out;
  out.x = v.x * r * ww.x;
  out.y = v.y * r * ww.y;
  out.z = v.z * r * ww.z;
  out.w = v.w * r * ww.w;
  if (o32) ((float4*)(o32 + (size_t)row * HH))[t] = out;
  __hip_bfloat16* d = o16 + (size_t)row * HH + t * 4;
  d[0] = __float2bfloat16(out.x);
  d[1] = __float2bfloat16(out.y);
  d[2] = __float2bfloat16(out.z);
  d[3] = __float2bfloat16(out.w);
}

// ---------------- Transpose-cast 64x64: in[R][C] fp32 -> out[C][R] bf16 ----
__global__ __launch_bounds__(256) void tcast_kernel(
    const float* __restrict__ in, __hip_bfloat16* __restrict__ out,
    int R, int C, size_t inBatch, size_t outBatch) {
  const float* ip = in + blockIdx.z * inBatch;
  __hip_bfloat16* op = out + blockIdx.z * outBatch;
  __shared__ float tile[64][65];
  int c0 = blockIdx.x * 64, r0 = blockIdx.y * 64;
  int tx = threadIdx.x & 15, ty = threadIdx.x >> 4;  // tx 0..15, ty 0..15
#pragma unroll
  for (int j = 0; j < 4; ++j) {
    int row = ty + j * 16;
    float4 v = *(const float4*)(ip + (size_t)(r0 + row) * C + c0 + tx * 4);
    tile[row][tx * 4 + 0] = v.x;
    tile[row][tx * 4 + 1] = v.y;
    tile[row][tx * 4 + 2] = v.z;
    tile[row][tx * 4 + 3] = v.w;
  }
  __syncthreads();
#pragma unroll
  for (int j = 0; j < 4; ++j) {
    int crow = ty + j * 16;
    ushort4 o;
    o.x = bf16_bits(tile[tx * 4 + 0][crow]);
    o.y = bf16_bits(tile[tx * 4 + 1][crow]);
    o.z = bf16_bits(tile[tx * 4 + 2][crow]);
    o.w = bf16_bits(tile[tx * 4 + 3][crow]);
    *(ushort4*)(op + (size_t)(c0 + crow) * R + r0 + tx * 4) = o;
  }
}

// ---------------- MFMA bf16 GEMM: C[M,N] = A[M,K] @ Bt[N,K]^T --------------
template <int MODE>
__global__ __launch_bounds__(256) void mfma_gemm(
    const __hip_bfloat16* __restrict__ A,
    const __hip_bfloat16* __restrict__ Bt,
    float* __restrict__ Cf, __hip_bfloat16* __restrict__ Cb,
    const float* __restrict__ addend, const float* __restrict__ bias,
    const int* __restrict__ counts, const int* __restrict__ offsets,
    const int* __restrict__ tos, int M0, int N, int K) {
  int e = blockIdx.z;
  int M = M0, off = 0;
  if (MODE >= 2) { M = counts[e]; off = offsets[e]; }
  int row0 = blockIdx.y * 128;
  if (row0 >= M) return;
  int n0 = blockIdx.x * 128;
  const __hip_bfloat16* Bte = Bt + (size_t)e * ((size_t)N * K);
  __shared__ __align__(16) __hip_bfloat16 sA[128 * 32];
  __shared__ __align__(16) __hip_bfloat16 sB[128 * 32];
  int t = threadIdx.x;
  int lane = t & 63;
  int wm = t >> 7, wn = (t >> 6) & 1;
  f32x4 acc[4][4] = {};

  int arow[2];
#pragma unroll
  for (int i = 0; i < 2; ++i) {
    int rg = row0 + i * 64 + (t >> 2);
    int ar;
    if (MODE == 2)      ar = (rg < M) ? tos[off + rg] : tos[off];
    else if (MODE == 3) ar = off + ((rg < M) ? rg : 0);
    else                ar = rg;
    arow[i] = ar;
  }
  int brow0 = n0 + (t >> 2);
  int kc = (t & 3) * 8;

  for (int k0 = 0; k0 < K; k0 += 32) {
#pragma unroll
    for (int i = 0; i < 2; ++i) {
      int r = i * 64 + (t >> 2);
      gload_lds16(A + (size_t)arow[i] * K + k0 + kc, sA + r * 32 + kc);
      gload_lds16(Bte + (size_t)(brow0 + i * 64) * K + k0 + kc, sB + r * 32 + kc);
    }
    __syncthreads();
    bf16x8 af[4], bfr[4];
#pragma unroll
    for (int mi = 0; mi < 4; ++mi)
      af[mi] = *(const bf16x8*)(sA + (wm * 64 + mi * 16 + (lane & 15)) * 32 + (lane >> 4) * 8);
#pragma unroll
    for (int ni = 0; ni < 4; ++ni)
      bfr[ni] = *(const bf16x8*)(sB + (wn * 64 + ni * 16 + (lane & 15)) * 32 + (lane >> 4) * 8);
#pragma unroll
    for (int mi = 0; mi < 4; ++mi)
#pragma unroll
      for (int ni = 0; ni < 4; ++ni)
        acc[mi][ni] = __builtin_amdgcn_mfma_f32_16x16x32_bf16(af[mi], bfr[ni], acc[mi][ni], 0, 0, 0);
    __syncthreads();
  }

#pragma unroll
  for (int mi = 0; mi < 4; ++mi) {
#pragma unroll
    for (int ni = 0; ni < 4; ++ni) {
      int col = n0 + wn * 64 + ni * 16 + (lane & 15);
#pragma unroll
      for (int j = 0; j < 4; ++j) {
        float v = acc[mi][ni][j];
        int rg = row0 + wm * 64 + mi * 16 + (lane >> 4) * 4 + j;
        if (MODE == 0) {
          Cf[(size_t)rg * N + col] = v;
        } else if (MODE == 1) {
          Cf[(size_t)rg * N + col] = v + addend[(size_t)rg * N + col];
        } else if (MODE == 2) {
          float other = __shfl_xor(v, 1);
          if (!(lane & 1) && rg < M) {
            float gate = fminf(v + bias[(size_t)e * N + col], LIMITV);
            float up = fminf(fmaxf(other + bias[(size_t)e * N + col + 1], -LIMITV), LIMITV);
            float glu = gate / (1.f + __expf(-gate * ALPHAV));
            Cb[(size_t)(off + rg) * (N / 2) + (col >> 1)] = __float2bfloat16((up + 1.f) * glu);
          }
        } else {
          if (rg < M)
            Cf[(size_t)(off + rg) * N + col] = v + bias[(size_t)e * N + col];
        }
      }
    }
  }
}

// ---------------- RoPE + hi/lo split cast ----------------------------------
__global__ __launch_bounds__(512) void rope_cast_kernel(
    const float* __restrict__ qkv, const float* __restrict__ sins,
    const float* __restrict__ coss,
    __hip_bfloat16* __restrict__ qhi, __hip_bfloat16* __restrict__ qlo,
    __hip_bfloat16* __restrict__ khi, __hip_bfloat16* __restrict__ klo) {
  int s = blockIdx.x, t = threadIdx.x;
  const float* rowp = qkv + (size_t)s * 1536;
  int hh = t >> 5, j = t & 31;
  float c = coss[s * 32 + j], sn = sins[s * 32 + j];
  {
    float xr = rowp[hh * 64 + j], xi = rowp[hh * 64 + 32 + j];
    float y0 = xr * c - xi * sn;
    float y1 = xr * sn + xi * c;
    size_t i0 = (size_t)s * 1024 + hh * 64 + j;
    __hip_bfloat16 h0 = __float2bfloat16(y0);
    __hip_bfloat16 h1 = __float2bfloat16(y1);
    qhi[i0] = h0;      qlo[i0] = __float2bfloat16(y0 - __bfloat162float(h0));
    qhi[i0 + 32] = h1; qlo[i0 + 32] = __float2bfloat16(y1 - __bfloat162float(h1));
  }
  if (t < 128) {
    int kh = t >> 5;
    float xr = rowp[1024 + kh * 64 + j], xi = rowp[1024 + kh * 64 + 32 + j];
    float y0 = xr * c - xi * sn;
    float y1 = xr * sn + xi * c;
    size_t i0 = (size_t)kh * 131072 + s * 64 + j;
    __hip_bfloat16 h0 = __float2bfloat16(y0);
    __hip_bfloat16 h1 = __float2bfloat16(y1);
    khi[i0] = h0;      klo[i0] = __float2bfloat16(y0 - __bfloat162float(h0));
    khi[i0 + 32] = h1; klo[i0 + 32] = __float2bfloat16(y1 - __bfloat162float(h1));
  }
}

// ---------------- V transpose: qkv fp32 v-part -> vT bf16 [4][64][2048] ----
__global__ void vtrans_kernel(const float* __restrict__ qkv,
                              __hip_bfloat16* __restrict__ vT) {
  __shared__ float tile[32][33];
  int kh = blockIdx.z;
  int d0 = blockIdx.x * 32;
  int s0 = blockIdx.y * 32;
  int tx = threadIdx.x & 31, ty = threadIdx.x >> 5;  // ty 0..7
#pragma unroll
  for (int j = 0; j < 4; ++j)
    tile[ty * 4 + j][tx] =
        qkv[(size_t)(s0 + ty * 4 + j) * 1536 + 1280 + kh * 64 + d0 + tx];
  __syncthreads();
#pragma unroll
  for (int j = 0; j < 4; ++j)
    vT[(size_t)kh * 131072 + (size_t)(d0 + ty * 4 + j) * 2048 + s0 + tx] =
        __float2bfloat16(tile[tx][ty * 4 + j]);
}

// ---------------- MFMA flash attention, fine kv-split, hi/lo precision -----
// grid (128 qtiles, 16 heads, 8 kv-chunks), 64 thr = 1 wave, 16 q-rows.
// Chunk ck covers kv-tiles [4ck, min(4ck+4, qb/4+1)). Partials to scratch.
__global__ __launch_bounds__(64) void mfma_attn(
    const __hip_bfloat16* __restrict__ qhi, const __hip_bfloat16* __restrict__ qlo,
    const __hip_bfloat16* __restrict__ khi, const __hip_bfloat16* __restrict__ klo,
    const __hip_bfloat16* __restrict__ vT,  // [4][64][S]
    float* __restrict__ pacc,               // [8][S][1024] unnormalized O
    float* __restrict__ pm,                 // [8][16][S]
    float* __restrict__ pl) {               // [8][16][S]
  __shared__ __align__(16) __hip_bfloat16 sPh[16 * 80];
  __shared__ __align__(16) __hip_bfloat16 sPl[16 * 80];
  int qb = blockIdx.x;
  int h = blockIdx.y, kh = h >> 2;
  int ck = blockIdx.z;
  if (16 * ck > qb) return;
  int lane = threadIdx.x;
  int qrow0 = qb * 16;
  const int koff = (lane >> 4) * 8;  // elems

  bf16x8 aqh[2], aql[2];
  {
    size_t qo = (size_t)(qrow0 + (lane & 15)) * 1024 + h * 64;
    aqh[0] = *(const bf16x8*)(qhi + qo + koff);
    aqh[1] = *(const bf16x8*)(qhi + qo + 32 + koff);
    aql[0] = *(const bf16x8*)(qlo + qo + koff);
    aql[1] = *(const bf16x8*)(qlo + qo + 32 + koff);
  }
  f32x4 acc_o[4] = {};
  float m[4] = {-1e30f, -1e30f, -1e30f, -1e30f};
  float l[4] = {};
  const size_t kbase = (size_t)kh * (SS * 64) + (size_t)(lane & 15) * 64 + koff;
  const __hip_bfloat16* khp = khi + kbase;
  const __hip_bfloat16* klp = klo + kbase;
  const __hip_bfloat16* vfp =
      vT + (size_t)kh * (64 * SS) + (size_t)(lane & 15) * SS + koff;

  int ntiles = qb / 4 + 1;
  int lastT = ntiles - 1;
  int t0 = 4 * ck;
  int t1 = 4 * ck + 4; if (t1 > ntiles) t1 = ntiles;

  for (int tile = t0; tile < t1; ++tile) {
    int kv0 = tile * 64;
    bool last = (tile == lastT);

    // S = Q K^T with hi/lo split
    f32x4 sacc[4] = {};
#pragma unroll
    for (int n = 0; n < 4; ++n) {
#pragma unroll
      for (int step = 0; step < 2; ++step) {
        size_t ko = (size_t)(kv0 + n * 16) * 64 + step * 32;
        bf16x8 bkh = *(const bf16x8*)(khp + ko);
        bf16x8 bkl = *(const bf16x8*)(klp + ko);
        sacc[n] = __builtin_amdgcn_mfma_f32_16x16x32_bf16(aqh[step], bkh, sacc[n], 0, 0, 0);
        sacc[n] = __builtin_amdgcn_mfma_f32_16x16x32_bf16(aqh[step], bkl, sacc[n], 0, 0, 0);
        sacc[n] = __builtin_amdgcn_mfma_f32_16x16x32_bf16(aql[step], bkh, sacc[n], 0, 0, 0);
      }
    }

    // online softmax per j-row (C layout: row=(lane>>4)*4+j, col=n*16+(lane&15))
    float alpha[4];
#pragma unroll
    for (int j = 0; j < 4; ++j) {
      int qr = qrow0 + (lane >> 4) * 4 + j;
      float sv[4];
#pragma unroll
      for (int n = 0; n < 4; ++n) {
        float s = sacc[n][j] * 0.125f;
        if (last && (kv0 + n * 16 + (lane & 15)) > qr) s = -1e30f;
        sv[n] = s;
      }
      float smax = fmaxf(fmaxf(sv[0], sv[1]), fmaxf(sv[2], sv[3]));
#pragma unroll
      for (int msk = 1; msk < 16; msk <<= 1) smax = fmaxf(smax, __shfl_xor(smax, msk));
      float mnew = fmaxf(m[j], smax);
      float a = __expf(m[j] - mnew);
      float rs = 0.f;
      int prow = (lane >> 4) * 4 + j;
#pragma unroll
      for (int n = 0; n < 4; ++n) {
        float p = __expf(sv[n] - mnew);
        rs += p;
        __hip_bfloat16 ph = __float2bfloat16(p);
        sPh[prow * 80 + n * 16 + (lane & 15)] = ph;
        sPl[prow * 80 + n * 16 + (lane & 15)] =
            __float2bfloat16(p - __bfloat162float(ph));
      }
#pragma unroll
      for (int msk = 1; msk < 16; msk <<= 1) rs += __shfl_xor(rs, msk);
      l[j] = l[j] * a + rs;
      m[j] = mnew;
      alpha[j] = a;
    }
#pragma unroll
    for (int n2 = 0; n2 < 4; ++n2)
#pragma unroll
      for (int j = 0; j < 4; ++j) acc_o[n2][j] *= alpha[j];

    // O += P V with hi/lo P (same-wave LDS, no barrier needed)
#pragma unroll
    for (int n2 = 0; n2 < 4; ++n2) {
#pragma unroll
      for (int step = 0; step < 2; ++step) {
        bf16x8 aph = *(const bf16x8*)(sPh + (lane & 15) * 80 + koff + step * 32);
        bf16x8 apl = *(const bf16x8*)(sPl + (lane & 15) * 80 + koff + step * 32);
        bf16x8 bv = *(const bf16x8*)(vfp + (size_t)(n2 * 16) * SS + kv0 + step * 32);
        acc_o[n2] = __builtin_amdgcn_mfma_f32_16x16x32_bf16(aph, bv, acc_o[n2], 0, 0, 0);
        acc_o[n2] = __builtin_amdgcn_mfma_f32_16x16x32_bf16(apl, bv, acc_o[n2], 0, 0, 0);
      }
    }
  }

  // store partials (unnormalized)
#pragma unroll
  for (int n2 = 0; n2 < 4; ++n2) {
#pragma unroll
    for (int j = 0; j < 4; ++j) {
      int row = qrow0 + (lane >> 4) * 4 + j;
      pacc[((size_t)ck * SS + row) * 1024 + h * 64 + n2 * 16 + (lane & 15)] = acc_o[n2][j];
    }
  }
  if ((lane & 15) == 0) {
#pragma unroll
    for (int j = 0; j < 4; ++j) {
      int row = qrow0 + (lane >> 4) * 4 + j;
      pm[(ck * 16 + h) * SS + row] = m[j];
      pl[(ck * 16 + h) * SS + row] = l[j];
    }
  }
}

// ---------------- Attention merge: combine <=8 kv-chunk partials -----------
__global__ __launch_bounds__(256) void attn_merge(
    const float* __restrict__ pacc, const float* __restrict__ pm,
    const float* __restrict__ pl, __hip_bfloat16* __restrict__ o) {
  int r = blockIdx.x;
  int t = threadIdx.x;
  int col = t * 4;
  int h = col >> 6;
  int nch = r / 256 + 1;
  float M = -1e30f;
  for (int c = 0; c < nch; ++c) M = fmaxf(M, pm[(c * 16 + h) * SS + r]);
  float L = 0.f;
  float4 acc = {0.f, 0.f, 0.f, 0.f};
  for (int c = 0; c < nch; ++c) {
    float w = __expf(pm[(c * 16 + h) * SS + r] - M);
    L += w * pl[(c * 16 + h) * SS + r];
    float4 a = *(const float4*)(pacc + ((size_t)c * SS + r) * 1024 + col);
    acc.x += w * a.x; acc.y += w * a.y; acc.z += w * a.z; acc.w += w * a.w;
  }
  float inv = 1.f / L;
  __hip_bfloat16* d = o + (size_t)r * 1024 + col;
  d[0] = __float2bfloat16(acc.x * inv);
  d[1] = __float2bfloat16(acc.y * inv);
  d[2] = __float2bfloat16(acc.z * inv);
  d[3] = __float2bfloat16(acc.w * inv);
}

// ---------------- Router ---------------------------------------------------
__global__ void router_kernel(const float* __restrict__ xn2,
                              const float* __restrict__ wr,
                              const float* __restrict__ br,
                              int* __restrict__ tok_e, float* __restrict__ tok_w,
                              int* __restrict__ counts) {
  int tok = blockIdx.x, lane = threadIdx.x;
  const float* x = xn2 + (size_t)tok * HH;
  float lg[NEXP];
#pragma unroll
  for (int e = 0; e < NEXP; ++e) {
    float p = 0.f;
    for (int d = lane; d < HH; d += 64) p += x[d] * wr[d * NEXP + e];
    p = wave_reduce_sum(p);
    lg[e] = p + br[e];
  }
  if (lane == 0) {
    int e0 = 0; float v0 = lg[0];
#pragma unroll
    for (int e = 1; e < NEXP; ++e) if (lg[e] > v0) { v0 = lg[e]; e0 = e; }
    int e1 = -1; float v1 = -1e30f;
#pragma unroll
    for (int e = 0; e < NEXP; ++e)
      if (e != e0 && lg[e] > v1) { v1 = lg[e]; e1 = e; }
    float z = __expf(v1 - v0);
    float w0 = 1.f / (1.f + z);
    tok_e[2 * tok] = e0; tok_e[2 * tok + 1] = e1;
    tok_w[2 * tok] = w0; tok_w[2 * tok + 1] = 1.f - w0;
    atomicAdd(&counts[e0], 1);
    atomicAdd(&counts[e1], 1);
  }
}

__global__ void offsets_kernel(const int* __restrict__ counts,
                               int* __restrict__ offsets, int* __restrict__ cursor) {
  int s = 0;
#pragma unroll
  for (int e = 0; e < NEXP; ++e) { offsets[e] = s; s += counts[e]; cursor[e] = 0; }
}

__global__ void scatter_kernel(const int* __restrict__ tok_e,
                               const int* __restrict__ offsets, int* __restrict__ cursor,
                               int* __restrict__ token_of_slot,
                               int* __restrict__ slot_of_token) {
  int tok = blockIdx.x * 64 + threadIdx.x;
#pragma unroll
  for (int s2 = 0; s2 < 2; ++s2) {
    int e = tok_e[2 * tok + s2];
    int pos = atomicAdd(&cursor[e], 1);
    int g = offsets[e] + pos;
    token_of_slot[g] = tok;
    slot_of_token[2 * tok + s2] = g;
  }
}

// ---------------- Final combine -------------------------------------------
__global__ void combine_kernel(const float* __restrict__ resid2,
                               const float* __restrict__ dout,
                               const int* __restrict__ slot_of_token,
                               const float* __restrict__ tok_w,
                               float* __restrict__ out) {
  int tok = blockIdx.x;
  int g0 = slot_of_token[2 * tok], g1 = slot_of_token[2 * tok + 1];
  float w0 = tok_w[2 * tok], w1 = tok_w[2 * tok + 1];
  int i = threadIdx.x;
  float4 r = ((const float4*)(resid2 + (size_t)tok * HH))[i];
  float4 a = ((const float4*)(dout + (size_t)g0 * HH))[i];
  float4 b = ((const float4*)(dout + (size_t)g1 * HH))[i];
  float4 o;
  o.x = r.x + w0 * a.x + w1 * b.x;
  o.y = r.y + w0 * a.y + w1 * b.y;
  o.z = r.z + w0 * a.z + w1 * b.z;
  o.w = r.w + w0 * a.w + w1 * b.w;
  ((float4*)(out + (size_t)tok * HH))[i] = o;
}

extern "C" void kernel_launch(void* const* d_in, const int* in_sizes, int n_in,
                              void* d_out, int out_size, void* d_ws, size_t ws_size,
                              hipStream_t stream) {
  const float* hidden = (const float*)d_in[0];
  const float* sins   = (const float*)d_in[1];
  const float* coss   = (const float*)d_in[2];
  const float* ln1_w  = (const float*)d_in[4];
  const float* ln2_w  = (const float*)d_in[5];
  const float* wq     = (const float*)d_in[6];
  const float* wk     = (const float*)d_in[7];
  const float* wv     = (const float*)d_in[8];
  const float* wo     = (const float*)d_in[9];
  const float* w_router = (const float*)d_in[10];
  const float* b_router = (const float*)d_in[11];
  const float* gup    = (const float*)d_in[12];
  const float* gub    = (const float*)d_in[13];
  const float* dp     = (const float*)d_in[14];
  const float* db     = (const float*)d_in[15];
  float* out = (float*)d_out;

  float* ws = (float*)d_ws;
  float* resid2 = ws;                                      // 2,097,152 f
  float* xn2    = resid2 + 2097152;                        // 2,097,152 f
  __hip_bfloat16* xn2b = (__hip_bfloat16*)(xn2 + 2097152); // 2M bf16
  float* pa = xn2 + 2097152 + 1048576;
  // phase A carve (dead after WO GEMM; reused as dpT in phase B)
  __hip_bfloat16* xn1b = (__hip_bfloat16*)pa;              // [0, 1,048,576) f
  __hip_bfloat16* qlo_b = (__hip_bfloat16*)pa;             // over xn1b (dead by rope)
  float* qkv = pa + 1048576;                               // [1,048,576, 4,194,304)
  __hip_bfloat16* qkvT = (__hip_bfloat16*)(pa + 4194304);  // [4,194,304, 4,980,736)
  __hip_bfloat16* woT  = qkvT + 1572864;                   // [4,980,736, 5,505,024)
  __hip_bfloat16* qhi_b = (__hip_bfloat16*)(pa + 5505024); // [5,505,024, 6,553,600)
  __hip_bfloat16* khi_b = qhi_b + 2097152;                 // [6,553,600, 6,815,744)
  __hip_bfloat16* vTb  = khi_b + 524288;                   // [6,815,744, 7,077,888)
  __hip_bfloat16* attnb = (__hip_bfloat16*)(pa + 7077888); // [7,077,888, 8,126,464)
  __hip_bfloat16* klo_b = (__hip_bfloat16*)(pa + 8126464); // [8,126,464, 8,388,608)
  __hip_bfloat16* dpT = (__hip_bfloat16*)pa;               // phase B: [0, 8,388,608)
  float* pb = pa + 8388608;
  __hip_bfloat16* gupT = (__hip_bfloat16*)pb;              // 33.55M bf16 (phase B)
  // attn partials alias gupT+gatedb region (phase A only, dead before tcast gup)
  float* pacc = pb;                                        // 8*2048*1024 = 16,777,216 f
  float* pm_b = pb + 16777216;                             // 262,144 f (in gatedb area)
  float* pl_b = pm_b + 262144;                             // 262,144 f
  __hip_bfloat16* gatedb = gupT + 33554432;                // 8.39M bf16
  float* dout = pb + 16777216 + 4194304;                   // 4,194,304 f
  float* tok_w = dout + 4194304;
  int* counts = (int*)(tok_w + 4096);
  int* offsets = counts + 8;
  int* cursor = offsets + 8;
  int* tok_e = cursor + 8;
  int* token_of_slot = tok_e + 4096;
  int* slot_of_token = token_of_slot + 4096;

  rmsnorm_kernel<<<SS, 256, 0, stream>>>(hidden, ln1_w, nullptr, xn1b);
  tcast_kernel<<<dim3(16, 16, 1), 256, 0, stream>>>(wq, qkvT, 1024, 1024, 0, 0);
  tcast_kernel<<<dim3(4, 16, 1), 256, 0, stream>>>(wk, qkvT + 1024 * 1024, 1024, 256, 0, 0);
  tcast_kernel<<<dim3(4, 16, 1), 256, 0, stream>>>(wv, qkvT + 1280 * 1024, 1024, 256, 0, 0);
  tcast_kernel<<<dim3(16, 16, 1), 256, 0, stream>>>(wo, woT, 1024, 1024, 0, 0);
  mfma_gemm<0><<<dim3(12, 16, 1), 256, 0, stream>>>(
      xn1b, qkvT, qkv, nullptr, nullptr, nullptr, nullptr, nullptr, nullptr, SS, 1536, 1024);
  rope_cast_kernel<<<SS, 512, 0, stream>>>(qkv, sins, coss, qhi_b, qlo_b, khi_b, klo_b);
  vtrans_kernel<<<dim3(2, 64, 4), 256, 0, stream>>>(qkv, vTb);
  mfma_attn<<<dim3(128, 16, 8), 64, 0, stream>>>(
      qhi_b, qlo_b, khi_b, klo_b, vTb, pacc, pm_b, pl_b);
  attn_merge<<<SS, 256, 0, stream>>>(pacc, pm_b, pl_b, attnb);
  mfma_gemm<1><<<dim3(8, 16, 1), 256, 0, stream>>>(
      attnb, woT, resid2, nullptr, hidden, nullptr, nullptr, nullptr, nullptr, SS, 1024, 1024);
  rmsnorm_kernel<<<SS, 256, 0, stream>>>(resid2, ln2_w, xn2, xn2b);
  tcast_kernel<<<dim3(16, 32, NEXP), 256, 0, stream>>>(
      dp, dpT, 2048, 1024, (size_t)2048 * 1024, (size_t)1024 * 2048);
  tcast_kernel<<<dim3(64, 16, NEXP), 256, 0, stream>>>(
      gup, gupT, 1024, 4096, (size_t)1024 * 4096, (size_t)4096 * 1024);
  hipMemsetAsync(counts, 0, 8 * sizeof(int), stream);
  router_kernel<<<SS, 64, 0, stream>>>(xn2, w_router, b_router, tok_e, tok_w, counts);
  offsets_kernel<<<1, 1, 0, stream>>>(counts, offsets, cursor);
  scatter_kernel<<<SS / 64, 64, 0, stream>>>(tok_e, offsets, cursor, token_of_slot, slot_of_token);
  mfma_gemm<2><<<dim3(32, 16, NEXP), 256, 0, stream>>>(
      xn2b, gupT, nullptr, gatedb, nullptr, gub, counts, offsets, token_of_slot, 0, 4096, 1024);
  mfma_gemm<3><<<dim3(8, 16, NEXP), 256, 0, stream>>>(
      gatedb, dpT, dout, nullptr, nullptr, db, counts, offsets, nullptr, 0, 1024, 2048);
  combine_kernel<<<SS, 256, 0, stream>>>(resid2, dout, slot_of_token, tok_w, out);
}

// Round 11
// 546.416 us; speedup vs baseline: 1.0891x; 1.0001x over previous
//
#include <hip/hip_runtime.h>
#include <hip/hip_bf16.h>
#include <math.h>

#define SS 2048
#define HH 1024
#define NHEADS 16
#define NKVH 4
#define HDIM 64
#define NEXP 8
#define FDIM 2048

static constexpr float EPSV   = 1e-6f;
static constexpr float ALPHAV = 1.702f;
static constexpr float LIMITV = 7.0f;

typedef __attribute__((ext_vector_type(8))) short bf16x8;
typedef __attribute__((ext_vector_type(4))) float f32x4;

__device__ __forceinline__ float wave_reduce_sum(float v) {
#pragma unroll
  for (int off = 32; off; off >>= 1) v += __shfl_xor(v, off);
  return v;
}

__device__ __forceinline__ unsigned short bf16_bits(float x) {
  __hip_bfloat16 h = __float2bfloat16(x);
  return *reinterpret_cast<unsigned short*>(&h);
}

__device__ __forceinline__ void gload_lds16(const __hip_bfloat16* g, __hip_bfloat16* s) {
  __builtin_amdgcn_global_load_lds(
      (const __attribute__((address_space(1))) void*)g,
      (__attribute__((address_space(3))) void*)s, 16, 0, 0);
}

// ---------------- RMSNorm: fp32 in, optional fp32 out + bf16 out -----------
__global__ void rmsnorm_kernel(const float* __restrict__ x,
                               const float* __restrict__ w,
                               float* __restrict__ o32,
                               __hip_bfloat16* __restrict__ o16) {
  int row = blockIdx.x;
  int t = threadIdx.x;
  const float4 v = ((const float4*)(x + (size_t)row * HH))[t];
  float ss = v.x * v.x + v.y * v.y + v.z * v.z + v.w * v.w;
  ss = wave_reduce_sum(ss);
  __shared__ float parts[4];
  if ((t & 63) == 0) parts[t >> 6] = ss;
  __syncthreads();
  float tot = parts[0] + parts[1] + parts[2] + parts[3];
  float r = rsqrtf(tot * (1.0f / HH) + EPSV);
  const float4 ww = ((const float4*)w)[t];
  float4 out;
  out.x = v.x * r * ww.x;
  out.y = v.y * r * ww.y;
  out.z = v.z * r * ww.z;
  out.w = v.w * r * ww.w;
  if (o32) ((float4*)(o32 + (size_t)row * HH))[t] = out;
  __hip_bfloat16* d = o16 + (size_t)row * HH + t * 4;
  d[0] = __float2bfloat16(out.x);
  d[1] = __float2bfloat16(out.y);
  d[2] = __float2bfloat16(out.z);
  d[3] = __float2bfloat16(out.w);
}

// ---------------- Transpose-cast 64x64: in[R][C] fp32 -> out[C][R] bf16 ----
__global__ __launch_bounds__(256) void tcast_kernel(
    const float* __restrict__ in, __hip_bfloat16* __restrict__ out,
    int R, int C, size_t inBatch, size_t outBatch) {
  const float* ip = in + blockIdx.z * inBatch;
  __hip_bfloat16* op = out + blockIdx.z * outBatch;
  __shared__ float tile[64][65];
  int c0 = blockIdx.x * 64, r0 = blockIdx.y * 64;
  int tx = threadIdx.x & 15, ty = threadIdx.x >> 4;  // tx 0..15, ty 0..15
#pragma unroll
  for (int j = 0; j < 4; ++j) {
    int row = ty + j * 16;
    float4 v = *(const float4*)(ip + (size_t)(r0 + row) * C + c0 + tx * 4);
    tile[row][tx * 4 + 0] = v.x;
    tile[row][tx * 4 + 1] = v.y;
    tile[row][tx * 4 + 2] = v.z;
    tile[row][tx * 4 + 3] = v.w;
  }
  __syncthreads();
#pragma unroll
  for (int j = 0; j < 4; ++j) {
    int crow = ty + j * 16;
    ushort4 o;
    o.x = bf16_bits(tile[tx * 4 + 0][crow]);
    o.y = bf16_bits(tile[tx * 4 + 1][crow]);
    o.z = bf16_bits(tile[tx * 4 + 2][crow]);
    o.w = bf16_bits(tile[tx * 4 + 3][crow]);
    *(ushort4*)(op + (size_t)(c0 + crow) * R + r0 + tx * 4) = o;
  }
}

// ---------------- MFMA bf16 GEMM: C[M,N] = A[M,K] @ Bt[N,K]^T --------------
template <int MODE>
__global__ __launch_bounds__(256) void mfma_gemm(
    const __hip_bfloat16* __restrict__ A,
    const __hip_bfloat16* __restrict__ Bt,
    float* __restrict__ Cf, __hip_bfloat16* __restrict__ Cb,
    const float* __restrict__ addend, const float* __restrict__ bias,
    const int* __restrict__ counts, const int* __restrict__ offsets,
    const int* __restrict__ tos, int M0, int N, int K) {
  int e = blockIdx.z;
  int M = M0, off = 0;
  if (MODE >= 2) { M = counts[e]; off = offsets[e]; }
  int row0 = blockIdx.y * 128;
  if (row0 >= M) return;
  int n0 = blockIdx.x * 128;
  const __hip_bfloat16* Bte = Bt + (size_t)e * ((size_t)N * K);
  __shared__ __align__(16) __hip_bfloat16 sA[128 * 32];
  __shared__ __align__(16) __hip_bfloat16 sB[128 * 32];
  int t = threadIdx.x;
  int lane = t & 63;
  int wm = t >> 7, wn = (t >> 6) & 1;
  f32x4 acc[4][4] = {};

  int arow[2];
#pragma unroll
  for (int i = 0; i < 2; ++i) {
    int rg = row0 + i * 64 + (t >> 2);
    int ar;
    if (MODE == 2)      ar = (rg < M) ? tos[off + rg] : tos[off];
    else if (MODE == 3) ar = off + ((rg < M) ? rg : 0);
    else                ar = rg;
    arow[i] = ar;
  }
  int brow0 = n0 + (t >> 2);
  int kc = (t & 3) * 8;

  for (int k0 = 0; k0 < K; k0 += 32) {
#pragma unroll
    for (int i = 0; i < 2; ++i) {
      int r = i * 64 + (t >> 2);
      gload_lds16(A + (size_t)arow[i] * K + k0 + kc, sA + r * 32 + kc);
      gload_lds16(Bte + (size_t)(brow0 + i * 64) * K + k0 + kc, sB + r * 32 + kc);
    }
    __syncthreads();
    bf16x8 af[4], bfr[4];
#pragma unroll
    for (int mi = 0; mi < 4; ++mi)
      af[mi] = *(const bf16x8*)(sA + (wm * 64 + mi * 16 + (lane & 15)) * 32 + (lane >> 4) * 8);
#pragma unroll
    for (int ni = 0; ni < 4; ++ni)
      bfr[ni] = *(const bf16x8*)(sB + (wn * 64 + ni * 16 + (lane & 15)) * 32 + (lane >> 4) * 8);
#pragma unroll
    for (int mi = 0; mi < 4; ++mi)
#pragma unroll
      for (int ni = 0; ni < 4; ++ni)
        acc[mi][ni] = __builtin_amdgcn_mfma_f32_16x16x32_bf16(af[mi], bfr[ni], acc[mi][ni], 0, 0, 0);
    __syncthreads();
  }

#pragma unroll
  for (int mi = 0; mi < 4; ++mi) {
#pragma unroll
    for (int ni = 0; ni < 4; ++ni) {
      int col = n0 + wn * 64 + ni * 16 + (lane & 15);
#pragma unroll
      for (int j = 0; j < 4; ++j) {
        float v = acc[mi][ni][j];
        int rg = row0 + wm * 64 + mi * 16 + (lane >> 4) * 4 + j;
        if (MODE == 0) {
          Cf[(size_t)rg * N + col] = v;
        } else if (MODE == 1) {
          Cf[(size_t)rg * N + col] = v + addend[(size_t)rg * N + col];
        } else if (MODE == 2) {
          float other = __shfl_xor(v, 1);
          if (!(lane & 1) && rg < M) {
            float gate = fminf(v + bias[(size_t)e * N + col], LIMITV);
            float up = fminf(fmaxf(other + bias[(size_t)e * N + col + 1], -LIMITV), LIMITV);
            float glu = gate / (1.f + __expf(-gate * ALPHAV));
            Cb[(size_t)(off + rg) * (N / 2) + (col >> 1)] = __float2bfloat16((up + 1.f) * glu);
          }
        } else {
          if (rg < M)
            Cf[(size_t)(off + rg) * N + col] = v + bias[(size_t)e * N + col];
        }
      }
    }
  }
}

// ---------------- RoPE + hi/lo split cast ----------------------------------
__global__ __launch_bounds__(512) void rope_cast_kernel(
    const float* __restrict__ qkv, const float* __restrict__ sins,
    const float* __restrict__ coss,
    __hip_bfloat16* __restrict__ qhi, __hip_bfloat16* __restrict__ qlo,
    __hip_bfloat16* __restrict__ khi, __hip_bfloat16* __restrict__ klo) {
  int s = blockIdx.x, t = threadIdx.x;
  const float* rowp = qkv + (size_t)s * 1536;
  int hh = t >> 5, j = t & 31;
  float c = coss[s * 32 + j], sn = sins[s * 32 + j];
  {
    float xr = rowp[hh * 64 + j], xi = rowp[hh * 64 + 32 + j];
    float y0 = xr * c - xi * sn;
    float y1 = xr * sn + xi * c;
    size_t i0 = (size_t)s * 1024 + hh * 64 + j;
    __hip_bfloat16 h0 = __float2bfloat16(y0);
    __hip_bfloat16 h1 = __float2bfloat16(y1);
    qhi[i0] = h0;      qlo[i0] = __float2bfloat16(y0 - __bfloat162float(h0));
    qhi[i0 + 32] = h1; qlo[i0 + 32] = __float2bfloat16(y1 - __bfloat162float(h1));
  }
  if (t < 128) {
    int kh = t >> 5;
    float xr = rowp[1024 + kh * 64 + j], xi = rowp[1024 + kh * 64 + 32 + j];
    float y0 = xr * c - xi * sn;
    float y1 = xr * sn + xi * c;
    size_t i0 = (size_t)kh * 131072 + s * 64 + j;
    __hip_bfloat16 h0 = __float2bfloat16(y0);
    __hip_bfloat16 h1 = __float2bfloat16(y1);
    khi[i0] = h0;      klo[i0] = __float2bfloat16(y0 - __bfloat162float(h0));
    khi[i0 + 32] = h1; klo[i0 + 32] = __float2bfloat16(y1 - __bfloat162float(h1));
  }
}

// ---------------- V transpose: qkv fp32 v-part -> vT bf16 [4][64][2048] ----
__global__ void vtrans_kernel(const float* __restrict__ qkv,
                              __hip_bfloat16* __restrict__ vT) {
  __shared__ float tile[32][33];
  int kh = blockIdx.z;
  int d0 = blockIdx.x * 32;
  int s0 = blockIdx.y * 32;
  int tx = threadIdx.x & 31, ty = threadIdx.x >> 5;  // ty 0..7
#pragma unroll
  for (int j = 0; j < 4; ++j)
    tile[ty * 4 + j][tx] =
        qkv[(size_t)(s0 + ty * 4 + j) * 1536 + 1280 + kh * 64 + d0 + tx];
  __syncthreads();
#pragma unroll
  for (int j = 0; j < 4; ++j)
    vT[(size_t)kh * 131072 + (size_t)(d0 + ty * 4 + j) * 2048 + s0 + tx] =
        __float2bfloat16(tile[tx][ty * 4 + j]);
}

// ---------------- attn helpers ---------------------------------------------
__device__ __forceinline__ void attn_qk(
    const bf16x8* aqh, const bf16x8* aql,
    const __hip_bfloat16* khp, const __hip_bfloat16* klp,
    int kv0, f32x4* sacc) {
#pragma unroll
  for (int n = 0; n < 4; ++n) {
#pragma unroll
    for (int step = 0; step < 2; ++step) {
      size_t ko = (size_t)(kv0 + n * 16) * 64 + step * 32;
      bf16x8 bkh = *(const bf16x8*)(khp + ko);
      bf16x8 bkl = *(const bf16x8*)(klp + ko);
      sacc[n] = __builtin_amdgcn_mfma_f32_16x16x32_bf16(aqh[step], bkh, sacc[n], 0, 0, 0);
      sacc[n] = __builtin_amdgcn_mfma_f32_16x16x32_bf16(aqh[step], bkl, sacc[n], 0, 0, 0);
      sacc[n] = __builtin_amdgcn_mfma_f32_16x16x32_bf16(aql[step], bkh, sacc[n], 0, 0, 0);
    }
  }
}

__device__ __forceinline__ void attn_softmax(
    f32x4* sacc, int kv0, bool last, int qrow0, int lane,
    float* m, float* l, f32x4* acc_o,
    __hip_bfloat16* sPh, __hip_bfloat16* sPl) {
  float alpha[4];
#pragma unroll
  for (int j = 0; j < 4; ++j) {
    int qr = qrow0 + (lane >> 4) * 4 + j;
    float sv[4];
#pragma unroll
    for (int n = 0; n < 4; ++n) {
      float s = sacc[n][j] * 0.125f;
      if (last && (kv0 + n * 16 + (lane & 15)) > qr) s = -1e30f;
      sv[n] = s;
    }
    float smax = fmaxf(fmaxf(sv[0], sv[1]), fmaxf(sv[2], sv[3]));
#pragma unroll
    for (int msk = 1; msk < 16; msk <<= 1) smax = fmaxf(smax, __shfl_xor(smax, msk));
    float mnew = fmaxf(m[j], smax);
    float a = __expf(m[j] - mnew);
    float rs = 0.f;
    int prow = (lane >> 4) * 4 + j;
#pragma unroll
    for (int n = 0; n < 4; ++n) {
      float p = __expf(sv[n] - mnew);
      rs += p;
      __hip_bfloat16 ph = __float2bfloat16(p);
      sPh[prow * 80 + n * 16 + (lane & 15)] = ph;
      sPl[prow * 80 + n * 16 + (lane & 15)] =
          __float2bfloat16(p - __bfloat162float(ph));
    }
#pragma unroll
    for (int msk = 1; msk < 16; msk <<= 1) rs += __shfl_xor(rs, msk);
    l[j] = l[j] * a + rs;
    m[j] = mnew;
    alpha[j] = a;
  }
#pragma unroll
  for (int n2 = 0; n2 < 4; ++n2)
#pragma unroll
    for (int j = 0; j < 4; ++j) acc_o[n2][j] *= alpha[j];
}

__device__ __forceinline__ void attn_pv(
    const __hip_bfloat16* sPh, const __hip_bfloat16* sPl,
    const __hip_bfloat16* vfp, int kv0, int lane, int koff, f32x4* acc_o) {
#pragma unroll
  for (int n2 = 0; n2 < 4; ++n2) {
#pragma unroll
    for (int step = 0; step < 2; ++step) {
      bf16x8 aph = *(const bf16x8*)(sPh + (lane & 15) * 80 + koff + step * 32);
      bf16x8 apl = *(const bf16x8*)(sPl + (lane & 15) * 80 + koff + step * 32);
      bf16x8 bv = *(const bf16x8*)(vfp + (size_t)(n2 * 16) * SS + kv0 + step * 32);
      acc_o[n2] = __builtin_amdgcn_mfma_f32_16x16x32_bf16(aph, bv, acc_o[n2], 0, 0, 0);
      acc_o[n2] = __builtin_amdgcn_mfma_f32_16x16x32_bf16(apl, bv, acc_o[n2], 0, 0, 0);
    }
  }
}

// ---------------- MFMA flash attention, kv-split, 2-tile ILP ---------------
// grid (128 qtiles, 16 heads, 8 kv-chunks), 64 thr = 1 wave, 16 q-rows.
// Chunk ck covers kv-tiles [4ck, min(4ck+4, qb/4+1)). Pairs of tiles are
// processed with both QK blocks issued up front; PV(t) overlaps softmax(t+1).
__global__ __launch_bounds__(64) void mfma_attn(
    const __hip_bfloat16* __restrict__ qhi, const __hip_bfloat16* __restrict__ qlo,
    const __hip_bfloat16* __restrict__ khi, const __hip_bfloat16* __restrict__ klo,
    const __hip_bfloat16* __restrict__ vT,  // [4][64][S]
    float* __restrict__ pacc,               // [8][S][1024] unnormalized O
    float* __restrict__ pm,                 // [8][16][S]
    float* __restrict__ pl) {               // [8][16][S]
  __shared__ __align__(16) __hip_bfloat16 sPh[2][16 * 80];
  __shared__ __align__(16) __hip_bfloat16 sPl[2][16 * 80];
  int qb = blockIdx.x;
  int h = blockIdx.y, kh = h >> 2;
  int ck = blockIdx.z;
  if (16 * ck > qb) return;
  int lane = threadIdx.x;
  int qrow0 = qb * 16;
  const int koff = (lane >> 4) * 8;  // elems

  bf16x8 aqh[2], aql[2];
  {
    size_t qo = (size_t)(qrow0 + (lane & 15)) * 1024 + h * 64;
    aqh[0] = *(const bf16x8*)(qhi + qo + koff);
    aqh[1] = *(const bf16x8*)(qhi + qo + 32 + koff);
    aql[0] = *(const bf16x8*)(qlo + qo + koff);
    aql[1] = *(const bf16x8*)(qlo + qo + 32 + koff);
  }
  f32x4 acc_o[4] = {};
  float m[4] = {-1e30f, -1e30f, -1e30f, -1e30f};
  float l[4] = {};
  const size_t kbase = (size_t)kh * (SS * 64) + (size_t)(lane & 15) * 64 + koff;
  const __hip_bfloat16* khp = khi + kbase;
  const __hip_bfloat16* klp = klo + kbase;
  const __hip_bfloat16* vfp =
      vT + (size_t)kh * (64 * SS) + (size_t)(lane & 15) * SS + koff;

  int ntiles = qb / 4 + 1;
  int lastT = ntiles - 1;
  int t0 = 4 * ck;
  int t1 = 4 * ck + 4; if (t1 > ntiles) t1 = ntiles;

  int tile = t0;
  for (; tile + 1 < t1; tile += 2) {
    int kv0a = tile * 64, kv0b = (tile + 1) * 64;
    // issue both QK blocks first (independent MFMA chains)
    f32x4 sa[4] = {}, sb[4] = {};
    attn_qk(aqh, aql, khp, klp, kv0a, sa);
    attn_qk(aqh, aql, khp, klp, kv0b, sb);
    // softmax(a) -> PV(a) overlaps softmax(b) on the VALU pipe
    attn_softmax(sa, kv0a, tile == lastT, qrow0, lane, m, l, acc_o, sPh[0], sPl[0]);
    attn_pv(sPh[0], sPl[0], vfp, kv0a, lane, koff, acc_o);
    attn_softmax(sb, kv0b, (tile + 1) == lastT, qrow0, lane, m, l, acc_o, sPh[1], sPl[1]);
    attn_pv(sPh[1], sPl[1], vfp, kv0b, lane, koff, acc_o);
  }
  if (tile < t1) {
    int kv0 = tile * 64;
    f32x4 sa[4] = {};
    attn_qk(aqh, aql, khp, klp, kv0, sa);
    attn_softmax(sa, kv0, tile == lastT, qrow0, lane, m, l, acc_o, sPh[0], sPl[0]);
    attn_pv(sPh[0], sPl[0], vfp, kv0, lane, koff, acc_o);
  }

  // store partials (unnormalized)
#pragma unroll
  for (int n2 = 0; n2 < 4; ++n2) {
#pragma unroll
    for (int j = 0; j < 4; ++j) {
      int row = qrow0 + (lane >> 4) * 4 + j;
      pacc[((size_t)ck * SS + row) * 1024 + h * 64 + n2 * 16 + (lane & 15)] = acc_o[n2][j];
    }
  }
  if ((lane & 15) == 0) {
#pragma unroll
    for (int j = 0; j < 4; ++j) {
      int row = qrow0 + (lane >> 4) * 4 + j;
      pm[(ck * 16 + h) * SS + row] = m[j];
      pl[(ck * 16 + h) * SS + row] = l[j];
    }
  }
}

// ---------------- Attention merge: combine <=8 kv-chunk partials -----------
__global__ __launch_bounds__(256) void attn_merge(
    const float* __restrict__ pacc, const float* __restrict__ pm,
    const float* __restrict__ pl, __hip_bfloat16* __restrict__ o) {
  int r = blockIdx.x;
  int t = threadIdx.x;
  int col = t * 4;
  int h = col >> 6;
  int nch = r / 256 + 1;
  float M = -1e30f;
  for (int c = 0; c < nch; ++c) M = fmaxf(M, pm[(c * 16 + h) * SS + r]);
  float L = 0.f;
  float4 acc = {0.f, 0.f, 0.f, 0.f};
  for (int c = 0; c < nch; ++c) {
    float w = __expf(pm[(c * 16 + h) * SS + r] - M);
    L += w * pl[(c * 16 + h) * SS + r];
    float4 a = *(const float4*)(pacc + ((size_t)c * SS + r) * 1024 + col);
    acc.x += w * a.x; acc.y += w * a.y; acc.z += w * a.z; acc.w += w * a.w;
  }
  float inv = 1.f / L;
  __hip_bfloat16* d = o + (size_t)r * 1024 + col;
  d[0] = __float2bfloat16(acc.x * inv);
  d[1] = __float2bfloat16(acc.y * inv);
  d[2] = __float2bfloat16(acc.z * inv);
  d[3] = __float2bfloat16(acc.w * inv);
}

// ---------------- Router ---------------------------------------------------
__global__ void router_kernel(const float* __restrict__ xn2,
                              const float* __restrict__ wr,
                              const float* __restrict__ br,
                              int* __restrict__ tok_e, float* __restrict__ tok_w,
                              int* __restrict__ counts) {
  int tok = blockIdx.x, lane = threadIdx.x;
  const float* x = xn2 + (size_t)tok * HH;
  float lg[NEXP];
#pragma unroll
  for (int e = 0; e < NEXP; ++e) {
    float p = 0.f;
    for (int d = lane; d < HH; d += 64) p += x[d] * wr[d * NEXP + e];
    p = wave_reduce_sum(p);
    lg[e] = p + br[e];
  }
  if (lane == 0) {
    int e0 = 0; float v0 = lg[0];
#pragma unroll
    for (int e = 1; e < NEXP; ++e) if (lg[e] > v0) { v0 = lg[e]; e0 = e; }
    int e1 = -1; float v1 = -1e30f;
#pragma unroll
    for (int e = 0; e < NEXP; ++e)
      if (e != e0 && lg[e] > v1) { v1 = lg[e]; e1 = e; }
    float z = __expf(v1 - v0);
    float w0 = 1.f / (1.f + z);
    tok_e[2 * tok] = e0; tok_e[2 * tok + 1] = e1;
    tok_w[2 * tok] = w0; tok_w[2 * tok + 1] = 1.f - w0;
    atomicAdd(&counts[e0], 1);
    atomicAdd(&counts[e1], 1);
  }
}

__global__ void offsets_kernel(const int* __restrict__ counts,
                               int* __restrict__ offsets, int* __restrict__ cursor) {
  int s = 0;
#pragma unroll
  for (int e = 0; e < NEXP; ++e) { offsets[e] = s; s += counts[e]; cursor[e] = 0; }
}

__global__ void scatter_kernel(const int* __restrict__ tok_e,
                               const int* __restrict__ offsets, int* __restrict__ cursor,
                               int* __restrict__ token_of_slot,
                               int* __restrict__ slot_of_token) {
  int tok = blockIdx.x * 64 + threadIdx.x;
#pragma unroll
  for (int s2 = 0; s2 < 2; ++s2) {
    int e = tok_e[2 * tok + s2];
    int pos = atomicAdd(&cursor[e], 1);
    int g = offsets[e] + pos;
    token_of_slot[g] = tok;
    slot_of_token[2 * tok + s2] = g;
  }
}

// ---------------- Final combine -------------------------------------------
__global__ void combine_kernel(const float* __restrict__ resid2,
                               const float* __restrict__ dout,
                               const int* __restrict__ slot_of_token,
                               const float* __restrict__ tok_w,
                               float* __restrict__ out) {
  int tok = blockIdx.x;
  int g0 = slot_of_token[2 * tok], g1 = slot_of_token[2 * tok + 1];
  float w0 = tok_w[2 * tok], w1 = tok_w[2 * tok + 1];
  int i = threadIdx.x;
  float4 r = ((const float4*)(resid2 + (size_t)tok * HH))[i];
  float4 a = ((const float4*)(dout + (size_t)g0 * HH))[i];
  float4 b = ((const float4*)(dout + (size_t)g1 * HH))[i];
  float4 o;
  o.x = r.x + w0 * a.x + w1 * b.x;
  o.y = r.y + w0 * a.y + w1 * b.y;
  o.z = r.z + w0 * a.z + w1 * b.z;
  o.w = r.w + w0 * a.w + w1 * b.w;
  ((float4*)(out + (size_t)tok * HH))[i] = o;
}

extern "C" void kernel_launch(void* const* d_in, const int* in_sizes, int n_in,
                              void* d_out, int out_size, void* d_ws, size_t ws_size,
                              hipStream_t stream) {
  const float* hidden = (const float*)d_in[0];
  const float* sins   = (const float*)d_in[1];
  const float* coss   = (const float*)d_in[2];
  const float* ln1_w  = (const float*)d_in[4];
  const float* ln2_w  = (const float*)d_in[5];
  const float* wq     = (const float*)d_in[6];
  const float* wk     = (const float*)d_in[7];
  const float* wv     = (const float*)d_in[8];
  const float* wo     = (const float*)d_in[9];
  const float* w_router = (const float*)d_in[10];
  const float* b_router = (const float*)d_in[11];
  const float* gup    = (const float*)d_in[12];
  const float* gub    = (const float*)d_in[13];
  const float* dp     = (const float*)d_in[14];
  const float* db     = (const float*)d_in[15];
  float* out = (float*)d_out;

  float* ws = (float*)d_ws;
  float* resid2 = ws;                                      // 2,097,152 f
  float* xn2    = resid2 + 2097152;                        // 2,097,152 f
  __hip_bfloat16* xn2b = (__hip_bfloat16*)(xn2 + 2097152); // 2M bf16
  float* pa = xn2 + 2097152 + 1048576;
  // phase A carve (dead after WO GEMM; reused as dpT in phase B)
  __hip_bfloat16* xn1b = (__hip_bfloat16*)pa;              // [0, 1,048,576) f
  __hip_bfloat16* qlo_b = (__hip_bfloat16*)pa;             // over xn1b (dead by rope)
  float* qkv = pa + 1048576;                               // [1,048,576, 4,194,304)
  __hip_bfloat16* qkvT = (__hip_bfloat16*)(pa + 4194304);  // [4,194,304, 4,980,736)
  __hip_bfloat16* woT  = qkvT + 1572864;                   // [4,980,736, 5,505,024)
  __hip_bfloat16* qhi_b = (__hip_bfloat16*)(pa + 5505024); // [5,505,024, 6,553,600)
  __hip_bfloat16* khi_b = qhi_b + 2097152;                 // [6,553,600, 6,815,744)
  __hip_bfloat16* vTb  = khi_b + 524288;                   // [6,815,744, 7,077,888)
  __hip_bfloat16* attnb = (__hip_bfloat16*)(pa + 7077888); // [7,077,888, 8,126,464)
  __hip_bfloat16* klo_b = (__hip_bfloat16*)(pa + 8126464); // [8,126,464, 8,388,608)
  __hip_bfloat16* dpT = (__hip_bfloat16*)pa;               // phase B: [0, 8,388,608)
  float* pb = pa + 8388608;
  __hip_bfloat16* gupT = (__hip_bfloat16*)pb;              // 33.55M bf16 (phase B)
  // attn partials alias gupT+gatedb region (phase A only, dead before tcast gup)
  float* pacc = pb;                                        // 8*2048*1024 = 16,777,216 f
  float* pm_b = pb + 16777216;                             // 262,144 f (in gatedb area)
  float* pl_b = pm_b + 262144;                             // 262,144 f
  __hip_bfloat16* gatedb = gupT + 33554432;                // 8.39M bf16
  float* dout = pb + 16777216 + 4194304;                   // 4,194,304 f
  float* tok_w = dout + 4194304;
  int* counts = (int*)(tok_w + 4096);
  int* offsets = counts + 8;
  int* cursor = offsets + 8;
  int* tok_e = cursor + 8;
  int* token_of_slot = tok_e + 4096;
  int* slot_of_token = token_of_slot + 4096;

  rmsnorm_kernel<<<SS, 256, 0, stream>>>(hidden, ln1_w, nullptr, xn1b);
  tcast_kernel<<<dim3(16, 16, 1), 256, 0, stream>>>(wq, qkvT, 1024, 1024, 0, 0);
  tcast_kernel<<<dim3(4, 16, 1), 256, 0, stream>>>(wk, qkvT + 1024 * 1024, 1024, 256, 0, 0);
  tcast_kernel<<<dim3(4, 16, 1), 256, 0, stream>>>(wv, qkvT + 1280 * 1024, 1024, 256, 0, 0);
  tcast_kernel<<<dim3(16, 16, 1), 256, 0, stream>>>(wo, woT, 1024, 1024, 0, 0);
  mfma_gemm<0><<<dim3(12, 16, 1), 256, 0, stream>>>(
      xn1b, qkvT, qkv, nullptr, nullptr, nullptr, nullptr, nullptr, nullptr, SS, 1536, 1024);
  rope_cast_kernel<<<SS, 512, 0, stream>>>(qkv, sins, coss, qhi_b, qlo_b, khi_b, klo_b);
  vtrans_kernel<<<dim3(2, 64, 4), 256, 0, stream>>>(qkv, vTb);
  mfma_attn<<<dim3(128, 16, 8), 64, 0, stream>>>(
      qhi_b, qlo_b, khi_b, klo_b, vTb, pacc, pm_b, pl_b);
  attn_merge<<<SS, 256, 0, stream>>>(pacc, pm_b, pl_b, attnb);
  mfma_gemm<1><<<dim3(8, 16, 1), 256, 0, stream>>>(
      attnb, woT, resid2, nullptr, hidden, nullptr, nullptr, nullptr, nullptr, SS, 1024, 1024);
  rmsnorm_kernel<<<SS, 256, 0, stream>>>(resid2, ln2_w, xn2, xn2b);
  tcast_kernel<<<dim3(16, 32, NEXP), 256, 0, stream>>>(
      dp, dpT, 2048, 1024, (size_t)2048 * 1024, (size_t)1024 * 2048);
  tcast_kernel<<<dim3(64, 16, NEXP), 256, 0, stream>>>(
      gup, gupT, 1024, 4096, (size_t)1024 * 4096, (size_t)4096 * 1024);
  hipMemsetAsync(counts, 0, 8 * sizeof(int), stream);
  router_kernel<<<SS, 64, 0, stream>>>(xn2, w_router, b_router, tok_e, tok_w, counts);
  offsets_kernel<<<1, 1, 0, stream>>>(counts, offsets, cursor);
  scatter_kernel<<<SS / 64, 64, 0, stream>>>(tok_e, offsets, cursor, token_of_slot, slot_of_token);
  mfma_gemm<2><<<dim3(32, 16, NEXP), 256, 0, stream>>>(
      xn2b, gupT, nullptr, gatedb, nullptr, gub, counts, offsets, token_of_slot, 0, 4096, 1024);
  mfma_gemm<3><<<dim3(8, 16, NEXP), 256, 0, stream>>>(
      gatedb, dpT, dout, nullptr, nullptr, db, counts, offsets, nullptr, 0, 1024, 2048);
  combine_kernel<<<SS, 256, 0, stream>>>(resid2, dout, slot_of_token, tok_w, out);
}